// Round 11
// baseline (14317.390 us; speedup 1.0000x reference)
//
#include <hip/hip_runtime.h>
#include <cstdint>
#include <cstddef>

// ============================================================================
// QuantGRU on MI355X — round 13
//
// r12 post-mortem (13.75ms, regression): last-wave-AGGREGATE didn't remove
// the 8-way atomic serialization (atomicAdd(cnt) == old atomicMax cost) and
// ADDED lredw writes + an 8-read aggregation in front of the publish.
//
// This round = r11 (12.40ms, best verified) + the salvageable r12 idea done
// right:
//  * keep r11's lred atomicMax merge VERBATIM; each wave's lane63 follows
//    its atomicMax with atomicAdd(cnt).  The 8th arriver reads the
//    ALREADY-MERGED lred (NCH loads) and publishes immediately — no barrier
//    on the publish path.  (LDS = in-order pipe: 8th add returning 7 =>
//    all 8 maxes are in the pipe before it; standard split-K last-block
//    pattern.)
//  * pollers moved BEFORE the barrier: they touch only remote slots +
//    lred atomicMax, so they start sampling ~250cy earlier, overlapping
//    the local reduce.
//  * barrier #1 deleted => ONE bar_lgkm per round (7/step vs 13).
//  * ring/ABA unchanged: reset of set (r+1)%3 at round r ordered against
//    round r-2 readbacks via bar(r-1); cnt[rset(r)] reset at r-1.
//  * value multisets identical => absmax exactly 0.06115723.
// ============================================================================

typedef int   v4i __attribute__((ext_vector_type(4)));
typedef float v4f __attribute__((ext_vector_type(4)));

#define T_STEPS 1024
#define OUT_MAIN_FLOATS (1024*64*256)          // 16,777,216
#define WXQ_DOUT_OFF 16842752                  // out_bytes(67,174,400) - 50,331,648
#define NWG 8

__device__ __forceinline__ float clamp128(float x) {
  return fminf(fmaxf(x, -128.0f), 127.0f);
}
__device__ __forceinline__ int permj(int j) {           // haste row -> pt row
  return j < 256 ? j + 256 : (j < 512 ? j - 256 : j);
}
__device__ __forceinline__ float sigmoidf_(float x) {
  return __fdividef(1.0f, 1.0f + __expf(-x));
}
__device__ __forceinline__ float tanhf_(float x) {
  float e = __expf(-2.0f * fabsf(x));
  float t = __fdividef(1.0f - e, 1.0f + e);
  return copysignf(t, x);
}
// monotone uint key for signed float max
__device__ __forceinline__ unsigned skey(float x) {
  unsigned u = __float_as_uint(x);
  return (u & 0x80000000u) ? ~u : (u | 0x80000000u);
}
__device__ __forceinline__ float sdec(unsigned k) {
  unsigned u = (k & 0x80000000u) ? (k ^ 0x80000000u) : ~k;
  return __uint_as_float(u);
}
__device__ __forceinline__ float wave_amax(float v) {
  #pragma unroll
  for (int m = 1; m <= 32; m <<= 1) v = fmaxf(v, __shfl_xor(v, m, 64));
  return v;
}

// VALU-only wave64 max reduction via DPP (r11-proven).  After the sequence
// lane 63 holds the max over all 64 lanes.  bound_ctrl=1 fills invalid lanes
// with 0 — the identity for our unsigned keys.
__device__ __forceinline__ unsigned dpp_wave_max(unsigned v) {
  unsigned t;
  t = (unsigned)__builtin_amdgcn_update_dpp(0, (int)v, 0x111, 0xf, 0xf, true);
  v = v > t ? v : t;   // row_shr:1
  t = (unsigned)__builtin_amdgcn_update_dpp(0, (int)v, 0x112, 0xf, 0xf, true);
  v = v > t ? v : t;   // row_shr:2
  t = (unsigned)__builtin_amdgcn_update_dpp(0, (int)v, 0x114, 0xf, 0xf, true);
  v = v > t ? v : t;   // row_shr:4
  t = (unsigned)__builtin_amdgcn_update_dpp(0, (int)v, 0x118, 0xf, 0xf, true);
  v = v > t ? v : t;   // row_shr:8 -> lane 15/31/47/63 hold row maxes
  t = (unsigned)__builtin_amdgcn_update_dpp(0, (int)v, 0x142, 0xf, 0xf, true);
  v = v > t ? v : t;   // row_bcast:15 -> lane 63 covers 32..63
  t = (unsigned)__builtin_amdgcn_update_dpp(0, (int)v, 0x143, 0xf, 0xf, true);
  v = v > t ? v : t;   // row_bcast:31 -> lane 63 covers 0..63
  return v;
}

// Barrier with LDS-only drain (r8-proven): no vmcnt wait => in-flight global
// stores/loads cross sync points.  sched_barrier stops hoisting (rule #18).
__device__ __forceinline__ void bar_lgkm() {
  asm volatile("s_waitcnt lgkmcnt(0)\n\ts_barrier" ::: "memory");
  __builtin_amdgcn_sched_barrier(0);
}

// Bounded 4-deep pipelined slot poll (r10-proven): up to 16 staggered 8B
// samples; returns 1 + value if the hi-word equalled tag for ALL ACTIVE
// LANES on some sample, else 0.  Caller's C-level fallback guarantees
// liveness regardless of asm load-flag semantics.
__device__ __forceinline__ int poll_burst(const unsigned long long* p,
                                          unsigned tag, unsigned* val) {
  unsigned out;
  int fnd;
  unsigned long long scr;
  asm volatile(
    "s_mov_b32 %[fnd], 0\n\t"
    "global_load_dwordx2 v[80:81], %[p], off sc1\n\t"
    "global_load_dwordx2 v[82:83], %[p], off sc0 sc1\n\t"
    "global_load_dwordx2 v[84:85], %[p], off sc1\n\t"
    "global_load_dwordx2 v[86:87], %[p], off sc0 sc1\n\t"

    "s_waitcnt vmcnt(3)\n\t"
    "v_cmp_eq_u32 vcc, %[tg], v81\n\t"
    "s_xor_b64 %[scr], vcc, exec\n\t"
    "s_cbranch_scc0 F0_%=\n\t"
    "global_load_dwordx2 v[80:81], %[p], off sc1\n\t"
    "s_waitcnt vmcnt(3)\n\t"
    "v_cmp_eq_u32 vcc, %[tg], v83\n\t"
    "s_xor_b64 %[scr], vcc, exec\n\t"
    "s_cbranch_scc0 F1_%=\n\t"
    "global_load_dwordx2 v[82:83], %[p], off sc0 sc1\n\t"
    "s_waitcnt vmcnt(3)\n\t"
    "v_cmp_eq_u32 vcc, %[tg], v85\n\t"
    "s_xor_b64 %[scr], vcc, exec\n\t"
    "s_cbranch_scc0 F2_%=\n\t"
    "global_load_dwordx2 v[84:85], %[p], off sc1\n\t"
    "s_waitcnt vmcnt(3)\n\t"
    "v_cmp_eq_u32 vcc, %[tg], v87\n\t"
    "s_xor_b64 %[scr], vcc, exec\n\t"
    "s_cbranch_scc0 F3_%=\n\t"
    "global_load_dwordx2 v[86:87], %[p], off sc0 sc1\n\t"

    "s_waitcnt vmcnt(3)\n\t"
    "v_cmp_eq_u32 vcc, %[tg], v81\n\t"
    "s_xor_b64 %[scr], vcc, exec\n\t"
    "s_cbranch_scc0 F0_%=\n\t"
    "global_load_dwordx2 v[80:81], %[p], off sc1\n\t"
    "s_waitcnt vmcnt(3)\n\t"
    "v_cmp_eq_u32 vcc, %[tg], v83\n\t"
    "s_xor_b64 %[scr], vcc, exec\n\t"
    "s_cbranch_scc0 F1_%=\n\t"
    "global_load_dwordx2 v[82:83], %[p], off sc0 sc1\n\t"
    "s_waitcnt vmcnt(3)\n\t"
    "v_cmp_eq_u32 vcc, %[tg], v85\n\t"
    "s_xor_b64 %[scr], vcc, exec\n\t"
    "s_cbranch_scc0 F2_%=\n\t"
    "global_load_dwordx2 v[84:85], %[p], off sc1\n\t"
    "s_waitcnt vmcnt(3)\n\t"
    "v_cmp_eq_u32 vcc, %[tg], v87\n\t"
    "s_xor_b64 %[scr], vcc, exec\n\t"
    "s_cbranch_scc0 F3_%=\n\t"
    "global_load_dwordx2 v[86:87], %[p], off sc0 sc1\n\t"

    "s_waitcnt vmcnt(3)\n\t"
    "v_cmp_eq_u32 vcc, %[tg], v81\n\t"
    "s_xor_b64 %[scr], vcc, exec\n\t"
    "s_cbranch_scc0 F0_%=\n\t"
    "s_waitcnt vmcnt(2)\n\t"
    "v_cmp_eq_u32 vcc, %[tg], v83\n\t"
    "s_xor_b64 %[scr], vcc, exec\n\t"
    "s_cbranch_scc0 F1_%=\n\t"
    "s_waitcnt vmcnt(1)\n\t"
    "v_cmp_eq_u32 vcc, %[tg], v85\n\t"
    "s_xor_b64 %[scr], vcc, exec\n\t"
    "s_cbranch_scc0 F2_%=\n\t"
    "s_waitcnt vmcnt(0)\n\t"
    "v_cmp_eq_u32 vcc, %[tg], v87\n\t"
    "s_xor_b64 %[scr], vcc, exec\n\t"
    "s_cbranch_scc0 F3_%=\n\t"
    "v_mov_b32 %[out], 0\n\t"
    "s_branch DN_%=\n\t"

    "F0_%=:\n\t"
    "v_mov_b32 %[out], v80\n\t"
    "s_mov_b32 %[fnd], 1\n\t"
    "s_branch DN_%=\n\t"
    "F1_%=:\n\t"
    "v_mov_b32 %[out], v82\n\t"
    "s_mov_b32 %[fnd], 1\n\t"
    "s_branch DN_%=\n\t"
    "F2_%=:\n\t"
    "v_mov_b32 %[out], v84\n\t"
    "s_mov_b32 %[fnd], 1\n\t"
    "s_branch DN_%=\n\t"
    "F3_%=:\n\t"
    "v_mov_b32 %[out], v86\n\t"
    "s_mov_b32 %[fnd], 1\n\t"
    "DN_%=:\n\t"
    "s_waitcnt vmcnt(0)"
    : [out]"=&v"(out), [fnd]"=&s"(fnd), [scr]"=&s"(scr)
    : [p]"v"(p), [tg]"v"(tag)
    : "vcc", "scc", "memory",
      "v80","v81","v82","v83","v84","v85","v86","v87");
  *val = out;
  return fnd;
}

#define MFMA_I8(a, b, c) __builtin_amdgcn_mfma_i32_16x16x64_i8(a, b, c, 0, 0, 0)

// ---------------- absmax over a float tensor (n4 = n/4) ----------------
__global__ void k_absmax(const float* __restrict__ p, int n4, unsigned* slot) {
  int i = blockIdx.x * blockDim.x + threadIdx.x;
  int stride = gridDim.x * blockDim.x;
  const v4f* p4 = (const v4f*)p;
  float m = 0.0f;
  for (; i < n4; i += stride) {
    v4f v = p4[i];
    m = fmaxf(m, fmaxf(fmaxf(fabsf(v[0]), fabsf(v[1])),
                       fmaxf(fabsf(v[2]), fabsf(v[3]))));
  }
  m = wave_amax(m);
  if ((threadIdx.x & 63) == 0) atomicMax(slot, __float_as_uint(m));
}

// ---------------- 768x256 weight -> int8 MFMA B-fragments ----------------
__global__ void k_frag(const float* __restrict__ src,
                       const unsigned* __restrict__ slots, int slot_idx,
                       signed char* __restrict__ dst) {
  int id = blockIdx.x * 256 + threadIdx.x;   // 0..49151
  float s = fmaxf(__uint_as_float(slots[slot_idx]) / 127.0f, 1e-8f);
  int bq   = id & 3;
  int lane = (id >> 2) & 63;
  int kc   = (id >> 8) & 3;
  int ct   = id >> 10;
  int n = ct * 16 + (lane & 15);
  int k = kc * 64 + (lane >> 4) * 16 + bq * 4;
  const float* p = src + permj(n) * 256 + k;
  int b0 = ((int)clamp128(rintf(p[0] / s))) & 255;
  int b1 = ((int)clamp128(rintf(p[1] / s))) & 255;
  int b2 = ((int)clamp128(rintf(p[2] / s))) & 255;
  int b3 = ((int)clamp128(rintf(p[3] / s))) & 255;
  ((int*)dst)[id] = b0 | (b1 << 8) | (b2 << 16) | (b3 << 24);
}

// ---------------- biases: reorder + fake-quant (dequantized fp32) ----------
__global__ void k_bias(const float* __restrict__ bih, const float* __restrict__ bhh,
                       const unsigned* __restrict__ slots, float* __restrict__ bqo) {
  int j = threadIdx.x;               // 0..767
  float s_bx = fmaxf(__uint_as_float(slots[3]) / 127.0f, 1e-8f);
  float s_br = fmaxf(__uint_as_float(slots[4]) / 127.0f, 1e-8f);
  int pr = permj(j);
  bqo[j]       = s_bx * clamp128(rintf(bih[pr] / s_bx));
  bqo[768 + j] = s_br * clamp128(rintf(bhh[pr] / s_br));
}

// ---------------- quantize x -> int8 ----------------
__global__ void k_xq(const float* __restrict__ x, const unsigned* __restrict__ slots,
                     signed char* __restrict__ xq8, int n4) {
  int i = blockIdx.x * blockDim.x + threadIdx.x;
  if (i >= n4) return;
  float s_x = fmaxf(__uint_as_float(slots[0]) / 127.0f, 1e-8f);
  v4f v = ((const v4f*)x)[i];
  int b0 = ((int)clamp128(rintf(v[0] / s_x))) & 255;
  int b1 = ((int)clamp128(rintf(v[1] / s_x))) & 255;
  int b2 = ((int)clamp128(rintf(v[2] / s_x))) & 255;
  int b3 = ((int)clamp128(rintf(v[3] / s_x))) & 255;
  ((int*)xq8)[i] = b0 | (b1 << 8) | (b2 << 16) | (b3 << 24);
}

// ---------------- Wx GEMM, int8 MFMA (both passes) ----------------
__global__ __launch_bounds__(1024) void k_wx_i8(
    const signed char* __restrict__ xq8, const signed char* __restrict__ wf,
    unsigned* __restrict__ slots, signed char* __restrict__ wxq, int mode) {
  const int t = blockIdx.x;
  const int tid = threadIdx.x, lane = tid & 63, w = tid >> 6;
  const int cl = lane & 15, lh = lane >> 4;

  v4i Bz[4], Br[4], Bn[4];
  #pragma unroll
  for (int kc = 0; kc < 4; ++kc) {
    Bz[kc] = *(const v4i*)(wf + (((w)*4      + kc) * 64 + lane) * 16);
    Br[kc] = *(const v4i*)(wf + (((w + 16)*4 + kc) * 64 + lane) * 16);
    Bn[kc] = *(const v4i*)(wf + (((w + 32)*4 + kc) * 64 + lane) * 16);
  }
  v4i acc[3][4];
  #pragma unroll
  for (int p = 0; p < 3; ++p)
    #pragma unroll
    for (int rt = 0; rt < 4; ++rt) acc[p][rt] = (v4i){0, 0, 0, 0};

  const signed char* xr = xq8 + t * 16384;
  #pragma unroll
  for (int kc = 0; kc < 4; ++kc)
    #pragma unroll
    for (int rt = 0; rt < 4; ++rt) {
      v4i A = *(const v4i*)(xr + (rt * 16 + cl) * 256 + kc * 64 + lh * 16);
      acc[0][rt] = MFMA_I8(A, Bz[kc], acc[0][rt]);
      acc[1][rt] = MFMA_I8(A, Br[kc], acc[1][rt]);
      acc[2][rt] = MFMA_I8(A, Bn[kc], acc[2][rt]);
    }

  if (mode == 0) {
    int mm = 0;
    #pragma unroll
    for (int p = 0; p < 3; ++p)
      #pragma unroll
      for (int rt = 0; rt < 4; ++rt)
        #pragma unroll
        for (int rg = 0; rg < 4; ++rg) mm = max(mm, abs(acc[p][rt][rg]));
    #pragma unroll
    for (int m = 1; m <= 32; m <<= 1) mm = max(mm, __shfl_xor(mm, m, 64));
    if (lane == 0) atomicMax((int*)(slots + 5), mm);
  } else {
    int islot = *(const int*)(slots + 5);
    float maxMf = (float)islot;
    float s_x = fmaxf(__uint_as_float(slots[0]) / 127.0f, 1e-8f);
    float s_W = fmaxf(__uint_as_float(slots[1]) / 127.0f, 1e-8f);
    float s_xW = s_x * s_W;
    float s_wx = fmaxf(s_xW * maxMf / 127.0f, 1e-8f);
    #pragma unroll
    for (int p = 0; p < 3; ++p)
      #pragma unroll
      for (int rt = 0; rt < 4; ++rt) {
        int dw = 0;
        #pragma unroll
        for (int rg = 0; rg < 4; ++rg) {
          float qf = clamp128(rintf((s_xW * (float)acc[p][rt][rg]) / s_wx));
          dw |= (((int)qf) & 255) << (rg * 8);
        }
        ((int*)wxq)[t * 12288 + p * 4096 + rt * 1024 + w * 64 + lh * 16 + cl] = dw;
      }
  }
}

// ---------------- cross-WG max exchange: last-arriver publish --------------
// Per round: DPP wave-max (all waves) -> lane63 atomicMax lred[rset][c]
// (r11-proven merge), then atomicAdd(cnt[rset]).  The 8th arriver reads the
// ALREADY-MERGED lred (LDS in-order pipe: all 8 maxes precede their adds)
// and publishes {tag,M} immediately — no barrier on the publish path.
// Pollers (burst + proven fallback) start BEFORE the barrier, overlapping
// the local reduce; they atomicMax remote values into lred.  tid32 resets
// set (rset+1)%3 (used next round; ordered vs round r-2 readers via
// bar(r-1) transitivity).  ONE bar_lgkm per round, then readback.
// ABA: our r+2 publish <- our bar(r+1) <- our pollers consumed remote r+1
// <- remote publish r+1 <- remote bar(r) <- remote consumed our round-r slot.
template <int NCH>
__device__ __forceinline__ void xchg(unsigned* keys, unsigned tag,
    unsigned (*lred)[8], unsigned* cnt, unsigned long long* gslot,
    int wg, int tid, int lane) {
  const int rset = tag % 3;
  const int par = tag & 1;
  #pragma unroll
  for (int c = 0; c < NCH; ++c) keys[c] = dpp_wave_max(keys[c]);
  if (lane == 63) {
    #pragma unroll
    for (int c = 0; c < NCH; ++c) atomicMax(&lred[rset][c], keys[c]);
    unsigned old = atomicAdd(&cnt[rset], 1u);
    if (old == 7u) {              // last arriver: lred fully merged; publish
      #pragma unroll
      for (int c = 0; c < NCH; ++c) {
        unsigned M = lred[rset][c];
        unsigned long long v =
            ((unsigned long long)tag << 32) | (unsigned long long)M;
        __hip_atomic_store(&gslot[(par * NWG + wg) * 8 + c], v,
                           __ATOMIC_RELAXED, __HIP_MEMORY_SCOPE_AGENT);
      }
    }
  } else if (tid == 32) {
    int ns = rset + 1; if (ns == 3) ns = 0;       // pre-zero next ring set
    #pragma unroll
    for (int c = 0; c < 8; ++c) lred[ns][c] = 0u;
    cnt[ns] = 0u;
  }
  if (tid >= 64 && tid < 64 + (NWG - 1) * NCH) {
    int idx = tid - 64;
    int owi = idx / NCH;
    int c = idx - owi * NCH;
    int ow = owi + (owi >= wg ? 1 : 0);
    unsigned long long* p = &gslot[(par * NWG + ow) * 8 + c];
    unsigned val;
    for (;;) {
      if (poll_burst(p, tag, &val)) break;           // fast staggered samples
      unsigned long long v =                         // proven liveness probe
          __hip_atomic_load(p, __ATOMIC_RELAXED, __HIP_MEMORY_SCOPE_AGENT);
      if ((unsigned)(v >> 32) == tag) { val = (unsigned)v; break; }
    }
    atomicMax(&lred[rset][c], val);
  }
  bar_lgkm();
  #pragma unroll
  for (int c = 0; c < NCH; ++c) keys[c] = lred[rset][c];
}

// ---------------- the recurrence: 8 workgroups, 8 batch rows each ----------
__global__ __launch_bounds__(512, 1) void k_recur8(
    const signed char* __restrict__ wxq, const signed char* __restrict__ brf,
    const float* __restrict__ bq, const unsigned* __restrict__ slots,
    const float* __restrict__ h0p, float* __restrict__ out,
    unsigned long long* __restrict__ gslot) {
  __shared__ signed char ah[16 * 272];     // rows 0..7 real, 8..15 zero
  __shared__ int zs[8 * 256];              // scattered acc, gate z [row][col]
  __shared__ int rs_[8 * 256];             // gate r
  __shared__ int ns_[8 * 256];             // gate n
  __shared__ unsigned lred[3][8];          // 3-set ring x 8 channels
  __shared__ unsigned cnt[3];              // 3-set ring arrival counters

  const int tid = threadIdx.x;
  const int lane = tid & 63;
  const int w = tid >> 6;                  // 8 waves; wave w: col tiles {2w,2w+1}
  const int cl = lane & 15;
  const int lh = lane >> 4;
  const int wg = blockIdx.x;               // 0..7 -> batch rows 8*wg..+7
  const int j = tid & 255;                 // elementwise column 0..255
  const int rblk = tid >> 8;               // 0/1: local rows 4*rblk..+3

  // zero lred + cnt + whole ah (rows 8..15 stay zero forever)
  if (tid < 24) ((unsigned*)lred)[tid] = 0u;
  if (tid >= 24 && tid < 27) cnt[tid - 24] = 0u;
  for (int i = tid; i < 1088; i += 512) ((int*)ah)[i] = 0;

  float s_x = fmaxf(__uint_as_float(slots[0]) / 127.0f, 1e-8f);
  float s_W = fmaxf(__uint_as_float(slots[1]) / 127.0f, 1e-8f);
  float s_R = fmaxf(__uint_as_float(slots[2]) / 127.0f, 1e-8f);
  float maxM0 = (float)(*(const int*)(slots + 5));
  float s_wx = fmaxf(s_x * s_W * maxM0 / 127.0f, 1e-8f);

  float bxz = bq[j], bxr = bq[j + 256], bxn = bq[j + 512];
  float brz = bq[768 + j], brr = bq[1024 + j], brn = bq[1280 + j];

  // R fragments, resident: 2 col-tiles x 3 gates x 4 kc
  v4i Bz[2][4], Br[2][4], Bn[2][4];
  #pragma unroll
  for (int cg = 0; cg < 2; ++cg) {
    int ct = w * 2 + cg;
    #pragma unroll
    for (int kc = 0; kc < 4; ++kc) {
      Bz[cg][kc] = *(const v4i*)(brf + ((ct * 4        + kc) * 64 + lane) * 16);
      Br[cg][kc] = *(const v4i*)(brf + (((ct + 16) * 4 + kc) * 64 + lane) * 16);
      Bn[cg][kc] = *(const v4i*)(brf + (((ct + 32) * 4 + kc) * 64 + lane) * 16);
    }
  }

  float h[4];
  #pragma unroll
  for (int rg = 0; rg < 4; ++rg)
    h[rg] = h0p[(wg * 8 + rblk * 4 + rg) * 256 + j];

  __syncthreads();                         // init (once; full sync fine)

  unsigned tag = 1;
  float sh;
  {
    float m = fmaxf(fmaxf(fabsf(h[0]), fabsf(h[1])),
                    fmaxf(fabsf(h[2]), fabsf(h[3])));
    unsigned kk[1] = {__float_as_uint(m)};
    xchg<1>(kk, tag++, lred, cnt, gslot, wg, tid, lane);
    sh = fmaxf(__uint_as_float(kk[0]) / 127.0f, 1e-8f);
    float ish = 1.0f / sh;
    #pragma unroll
    for (int rg = 0; rg < 4; ++rg)
      ah[(rblk * 4 + rg) * 272 + j] = (signed char)(int)rintf(h[rg] * ish);
    bar_lgkm();
  }

  // wxq dword index: global rows 8wg+4rblk..+3 = rt*16 + lhb*4..+3
  const int rt_ = wg >> 1;
  const int lhb = ((wg & 1) << 1) | rblk;
  const int widx0 = rt_ * 1024 + (j >> 4) * 64 + lhb * 16 + (j & 15);

  for (int t = 0; t < T_STEPS; ++t) {
    // Wx code dwords for this thread's 4 rows x 3 gates
    const int* wxi = (const int*)wxq + (size_t)t * 12288 + widx0;
    int wvz = wxi[0];
    int wvr = wxi[4096];
    int wvn = wxi[8192];

    // ---- GEMM: rows 0..7 real (rows 8..15 of ah are zero) ----
    v4i aZ[2] = {(v4i){0,0,0,0}, (v4i){0,0,0,0}};
    v4i aR[2] = {(v4i){0,0,0,0}, (v4i){0,0,0,0}};
    v4i aN[2] = {(v4i){0,0,0,0}, (v4i){0,0,0,0}};
    #pragma unroll
    for (int kc = 0; kc < 4; ++kc) {
      v4i A = *(const v4i*)(ah + cl * 272 + kc * 64 + lh * 16);
      #pragma unroll
      for (int cg = 0; cg < 2; ++cg) {
        aZ[cg] = MFMA_I8(A, Bz[cg][kc], aZ[cg]);
        aR[cg] = MFMA_I8(A, Br[cg][kc], aR[cg]);
        aN[cg] = MFMA_I8(A, Bn[cg][kc], aN[cg]);
      }
    }

    // scatter real accs (lanes 0..31 hold rows 0..7) into LDS; the round's
    // barrier orders these writes before the stage-B reads.
    if (lane < 32) {
      #pragma unroll
      for (int cg = 0; cg < 2; ++cg) {
        int jj = (w * 2 + cg) * 16 + cl;
        #pragma unroll
        for (int rg = 0; rg < 4; ++rg) {
          int row = lh * 4 + rg;
          zs[row * 256 + jj] = aZ[cg][rg];
          rs_[row * 256 + jj] = aR[cg][rg];
          ns_[row * 256 + jj] = aN[cg][rg];
        }
      }
    }

    // ---- R1: global max|acc| (zero rows contribute exactly 0) ----
    int mm = 0;
    #pragma unroll
    for (int cg = 0; cg < 2; ++cg)
      #pragma unroll
      for (int rg = 0; rg < 4; ++rg)
        mm = max(mm, max(abs(aZ[cg][rg]),
                         max(abs(aR[cg][rg]), abs(aN[cg][rg]))));
    unsigned kk[5];
    kk[0] = (unsigned)mm;
    xchg<1>(kk, tag++, lred, cnt, gslot, wg, tid, lane);
    float maxMf = (float)(int)kk[0];
    float s_Rh = fmaxf(sh * s_R * maxMf / 127.0f, 1e-8f);
    float fRh = (sh * s_R) / s_Rh;

    // ---- stage B: z_pre, r_pre, Rh_n+br_n + abs/signed maxes ----
    float zp[4], rp[4], nb[4];
    float az = 0.0f, ar = 0.0f, an = 0.0f;
    float mzs = -3.402823466e38f, mrs = -3.402823466e38f;
    #pragma unroll
    for (int rg = 0; rg < 4; ++rg) {
      int row = rblk * 4 + rg;
      float Rz = s_Rh * rintf((float)zs[row * 256 + j] * fRh);
      float Rr = s_Rh * rintf((float)rs_[row * 256 + j] * fRh);
      float Rn = s_Rh * rintf((float)ns_[row * 256 + j] * fRh);
      float wz = s_wx * (float)((signed char)(wvz >> (rg * 8)));
      float wr = s_wx * (float)((signed char)(wvr >> (rg * 8)));
      float a1 = ((wz + bxz) + Rz) + brz;
      float a2 = ((wr + bxr) + Rr) + brr;
      float a3 = Rn + brn;
      zp[rg] = a1; rp[rg] = a2; nb[rg] = a3;
      az = fmaxf(az, fabsf(a1)); ar = fmaxf(ar, fabsf(a2));
      an = fmaxf(an, fabsf(a3));
      mzs = fmaxf(mzs, a1); mrs = fmaxf(mrs, a2);
    }
    kk[0] = __float_as_uint(az); kk[1] = __float_as_uint(ar);
    kk[2] = __float_as_uint(an); kk[3] = skey(mzs); kk[4] = skey(mrs);
    xchg<5>(kk, tag++, lred, cnt, gslot, wg, tid, lane);
    float s1 = fmaxf(__uint_as_float(kk[0]) / 127.0f, 1e-8f), i1 = 1.0f / s1;
    float s2 = fmaxf(__uint_as_float(kk[1]) / 127.0f, 1e-8f), i2 = 1.0f / s2;
    float s3 = fmaxf(__uint_as_float(kk[2]) / 127.0f, 1e-8f), i3 = 1.0f / s3;
    float zq_max = s1 * rintf(sdec(kk[3]) * i1);
    float rq_max = s2 * rintf(sdec(kk[4]) * i2);
    float s4 = fmaxf(sigmoidf_(zq_max) / 127.0f, 1e-8f), i4 = 1.0f / s4;
    float s5 = fmaxf(sigmoidf_(rq_max) / 127.0f, 1e-8f), i5 = 1.0f / s5;

    // ---- stage C: z final, rRh ----
    float zf[4], rr_[4];
    float m6 = 0.0f;
    #pragma unroll
    for (int rg = 0; rg < 4; ++rg) {
      float zq = s1 * rintf(zp[rg] * i1);
      float rq = s2 * rintf(rp[rg] * i2);
      float zv = sigmoidf_(zq);
      float rv = sigmoidf_(rq);
      zf[rg] = s4 * rintf(zv * i4);
      float rq2 = s5 * rintf(rv * i5);
      float nbq = s3 * rintf(nb[rg] * i3);
      float rr = rq2 * nbq;
      rr_[rg] = rr;
      m6 = fmaxf(m6, fabsf(rr));
    }
    kk[0] = __float_as_uint(m6);
    xchg<1>(kk, tag++, lred, cnt, gslot, wg, tid, lane);
    float s6 = fmaxf(__uint_as_float(kk[0]) / 127.0f, 1e-8f), i6 = 1.0f / s6;

    // ---- stage D: g_pre ----
    float gp[4];
    float m7 = 0.0f;
    #pragma unroll
    for (int rg = 0; rg < 4; ++rg) {
      float rrq = s6 * rintf(rr_[rg] * i6);
      float wn = s_wx * (float)((signed char)(wvn >> (rg * 8)));
      float g = (wn + bxn) + rrq;
      gp[rg] = g;
      m7 = fmaxf(m7, fabsf(g));
    }
    kk[0] = __float_as_uint(m7);
    xchg<1>(kk, tag++, lred, cnt, gslot, wg, tid, lane);
    float m7g = __uint_as_float(kk[0]);
    float s7 = fmaxf(m7g / 127.0f, 1e-8f), i7 = 1.0f / s7;
    float gq_max = s7 * rintf(m7g * i7);
    float s8 = fmaxf(tanhf_(gq_max) / 127.0f, 1e-8f), i8v = 1.0f / s8;

    // ---- stage E: g, old/new contribs ----
    float ov[4], nv[4];
    float mo = 0.0f, mn = 0.0f;
    #pragma unroll
    for (int rg = 0; rg < 4; ++rg) {
      float gpq = s7 * rintf(gp[rg] * i7);
      float gv = tanhf_(gpq);
      float gq = s8 * rintf(gv * i8v);
      float o = zf[rg] * h[rg];
      float n = (1.0f - zf[rg]) * gq;
      ov[rg] = o; nv[rg] = n;
      mo = fmaxf(mo, fabsf(o)); mn = fmaxf(mn, fabsf(n));
    }
    kk[0] = __float_as_uint(mo); kk[1] = __float_as_uint(mn);
    xchg<2>(kk, tag++, lred, cnt, gslot, wg, tid, lane);
    float s9  = fmaxf(__uint_as_float(kk[0]) / 127.0f, 1e-8f), i9  = 1.0f / s9;
    float s10 = fmaxf(__uint_as_float(kk[1]) / 127.0f, 1e-8f), i10 = 1.0f / s10;

    // ---- stage F: h_new, write output ----
    float mh = 0.0f;
    #pragma unroll
    for (int rg = 0; rg < 4; ++rg) {
      float oq = s9  * rintf(ov[rg] * i9);
      float nq = s10 * rintf(nv[rg] * i10);
      float hn = oq + nq;
      h[rg] = hn;
      mh = fmaxf(mh, fabsf(hn));
      out[t * 16384 + (wg * 8 + rblk * 4 + rg) * 256 + j] = hn;
    }
    kk[0] = __float_as_uint(mh);
    xchg<1>(kk, tag++, lred, cnt, gslot, wg, tid, lane);
    sh = fmaxf(__uint_as_float(kk[0]) / 127.0f, 1e-8f);
    float ish = 1.0f / sh;
    #pragma unroll
    for (int rg = 0; rg < 4; ++rg)
      ah[(rblk * 4 + rg) * 272 + j] = (signed char)(int)rintf(h[rg] * ish);
    bar_lgkm();                            // ah ready for next step
  }

  // h_last
  #pragma unroll
  for (int rg = 0; rg < 4; ++rg)
    out[OUT_MAIN_FLOATS + (wg * 8 + rblk * 4 + rg) * 256 + j] = h[rg];
}

// ============================================================================
extern "C" void kernel_launch(void* const* d_in, const int* in_sizes, int n_in,
                              void* d_out, int out_size, void* d_ws, size_t ws_size,
                              hipStream_t stream) {
  const float* x   = (const float*)d_in[0];   // (1024,64,256)
  const float* wih = (const float*)d_in[1];   // (768,256)
  const float* whh = (const float*)d_in[2];   // (768,256)
  const float* bih = (const float*)d_in[3];   // (768,)
  const float* bhh = (const float*)d_in[4];   // (768,)
  const float* h0  = (const float*)d_in[5];   // (64,256)
  float* out = (float*)d_out;

  // d_ws layout: [0..255] absmax slots; [512..1535] tagged exchange slots
  // (2 parity x 8 wg x 8 ch x 8B = 1024B, 64B line per WG); [4096..] bq;
  // [10240..] fragment buffer F (196,608B).
  unsigned* slots = (unsigned*)d_ws;
  unsigned long long* gslot = (unsigned long long*)((char*)d_ws + 512);
  float* bq       = (float*)((char*)d_ws + 4096);
  signed char* F  = (signed char*)d_ws + 10240;

  signed char* wxq = (signed char*)d_out + WXQ_DOUT_OFF; // tail of d_out
  signed char* xq8 = (signed char*)d_out;                // head (dead later)

  hipMemsetAsync(d_ws, 0, 4096, stream);

  k_absmax<<<dim3(1024), dim3(256), 0, stream>>>(x,   16777216 / 4, slots + 0);
  k_absmax<<<dim3(96),   dim3(256), 0, stream>>>(wih, 196608 / 4,   slots + 1);
  k_absmax<<<dim3(96),   dim3(256), 0, stream>>>(whh, 196608 / 4,   slots + 2);
  k_absmax<<<dim3(1),    dim3(256), 0, stream>>>(bih, 768 / 4,      slots + 3);
  k_absmax<<<dim3(1),    dim3(256), 0, stream>>>(bhh, 768 / 4,      slots + 4);

  k_frag<<<dim3(192), dim3(256), 0, stream>>>(wih, slots, 1, F);   // W frags
  k_bias<<<dim3(1), dim3(768), 0, stream>>>(bih, bhh, slots, bq);
  k_xq<<<dim3(16384), dim3(256), 0, stream>>>(x, slots, xq8, 4194304);

  k_wx_i8<<<dim3(1024), dim3(1024), 0, stream>>>(xq8, F, slots, wxq, 0);
  k_wx_i8<<<dim3(1024), dim3(1024), 0, stream>>>(xq8, F, slots, wxq, 1);

  k_frag<<<dim3(192), dim3(256), 0, stream>>>(whh, slots, 2, F);   // R frags

  k_recur8<<<dim3(NWG), dim3(512), 0, stream>>>(wxq, F, bq, slots, h0, out,
                                                gslot);
}

// Round 12
// 12700.329 us; speedup vs baseline: 1.1273x; 1.1273x over previous
//
#include <hip/hip_runtime.h>
#include <cstdint>
#include <cstddef>

// ============================================================================
// QuantGRU on MI355X — round 14 (revert to round 11, best verified: 12.70ms)
//
// r12 (13.75ms) and r13 (14.0ms) post-mortems: both one-barrier exchange
// variants serialize the publish into a single-lane dependent chain off the
// slowest wave (atomics + LDS-load latency + stores ~500cy) where r11 pays a
// ~150cy barrier and publishes in PARALLEL (NCH threads, one store each).
// Parallel-publish-after-barrier is the cheapest structure measured.
//
// r11 structure (all components individually validated):
//  * DPP wave-max reduce (VALU-only, no ds_bpermute)      [r11: -0.17us/rd]
//  * lane63 LDS atomicMax merge; 2 lgkm-only barriers     [r8: vmcnt-free]
//  * parallel publish (tid<NCH), relaxed AGENT store      [r2-proven]
//  * 4-deep pipelined burst poll + proven fallback probe  [r10: -0.06us/rd]
//  * 3-ring LDS sets + parity-2 slots + monotone tags => no ABA
//  * 6 rounds/step are algorithmically forced (serial fake-quant scales)
//  * numerics byte-identical (absmax exactly 0.06115723)
// ============================================================================

typedef int   v4i __attribute__((ext_vector_type(4)));
typedef float v4f __attribute__((ext_vector_type(4)));

#define T_STEPS 1024
#define OUT_MAIN_FLOATS (1024*64*256)          // 16,777,216
#define WXQ_DOUT_OFF 16842752                  // out_bytes(67,174,400) - 50,331,648
#define NWG 8

__device__ __forceinline__ float clamp128(float x) {
  return fminf(fmaxf(x, -128.0f), 127.0f);
}
__device__ __forceinline__ int permj(int j) {           // haste row -> pt row
  return j < 256 ? j + 256 : (j < 512 ? j - 256 : j);
}
__device__ __forceinline__ float sigmoidf_(float x) {
  return __fdividef(1.0f, 1.0f + __expf(-x));
}
__device__ __forceinline__ float tanhf_(float x) {
  float e = __expf(-2.0f * fabsf(x));
  float t = __fdividef(1.0f - e, 1.0f + e);
  return copysignf(t, x);
}
// monotone uint key for signed float max
__device__ __forceinline__ unsigned skey(float x) {
  unsigned u = __float_as_uint(x);
  return (u & 0x80000000u) ? ~u : (u | 0x80000000u);
}
__device__ __forceinline__ float sdec(unsigned k) {
  unsigned u = (k & 0x80000000u) ? (k ^ 0x80000000u) : ~k;
  return __uint_as_float(u);
}
__device__ __forceinline__ float wave_amax(float v) {
  #pragma unroll
  for (int m = 1; m <= 32; m <<= 1) v = fmaxf(v, __shfl_xor(v, m, 64));
  return v;
}

// VALU-only wave64 max reduction via DPP (r11-proven).  After the sequence
// lane 63 holds the max over all 64 lanes.  bound_ctrl=1 fills invalid lanes
// with 0 — the identity for our unsigned keys.
__device__ __forceinline__ unsigned dpp_wave_max(unsigned v) {
  unsigned t;
  t = (unsigned)__builtin_amdgcn_update_dpp(0, (int)v, 0x111, 0xf, 0xf, true);
  v = v > t ? v : t;   // row_shr:1
  t = (unsigned)__builtin_amdgcn_update_dpp(0, (int)v, 0x112, 0xf, 0xf, true);
  v = v > t ? v : t;   // row_shr:2
  t = (unsigned)__builtin_amdgcn_update_dpp(0, (int)v, 0x114, 0xf, 0xf, true);
  v = v > t ? v : t;   // row_shr:4
  t = (unsigned)__builtin_amdgcn_update_dpp(0, (int)v, 0x118, 0xf, 0xf, true);
  v = v > t ? v : t;   // row_shr:8 -> lane 15/31/47/63 hold row maxes
  t = (unsigned)__builtin_amdgcn_update_dpp(0, (int)v, 0x142, 0xf, 0xf, true);
  v = v > t ? v : t;   // row_bcast:15 -> lane 63 covers 32..63
  t = (unsigned)__builtin_amdgcn_update_dpp(0, (int)v, 0x143, 0xf, 0xf, true);
  v = v > t ? v : t;   // row_bcast:31 -> lane 63 covers 0..63
  return v;
}

// Barrier with LDS-only drain (r8-proven): no vmcnt wait => in-flight global
// stores/loads cross sync points.  sched_barrier stops hoisting (rule #18).
__device__ __forceinline__ void bar_lgkm() {
  asm volatile("s_waitcnt lgkmcnt(0)\n\ts_barrier" ::: "memory");
  __builtin_amdgcn_sched_barrier(0);
}

// Bounded 4-deep pipelined slot poll (r10-proven): up to 16 staggered 8B
// samples; returns 1 + value if the hi-word equalled tag for ALL ACTIVE
// LANES on some sample, else 0.  Caller's C-level fallback guarantees
// liveness regardless of asm load-flag semantics.
__device__ __forceinline__ int poll_burst(const unsigned long long* p,
                                          unsigned tag, unsigned* val) {
  unsigned out;
  int fnd;
  unsigned long long scr;
  asm volatile(
    "s_mov_b32 %[fnd], 0\n\t"
    "global_load_dwordx2 v[80:81], %[p], off sc1\n\t"
    "global_load_dwordx2 v[82:83], %[p], off sc0 sc1\n\t"
    "global_load_dwordx2 v[84:85], %[p], off sc1\n\t"
    "global_load_dwordx2 v[86:87], %[p], off sc0 sc1\n\t"

    "s_waitcnt vmcnt(3)\n\t"
    "v_cmp_eq_u32 vcc, %[tg], v81\n\t"
    "s_xor_b64 %[scr], vcc, exec\n\t"
    "s_cbranch_scc0 F0_%=\n\t"
    "global_load_dwordx2 v[80:81], %[p], off sc1\n\t"
    "s_waitcnt vmcnt(3)\n\t"
    "v_cmp_eq_u32 vcc, %[tg], v83\n\t"
    "s_xor_b64 %[scr], vcc, exec\n\t"
    "s_cbranch_scc0 F1_%=\n\t"
    "global_load_dwordx2 v[82:83], %[p], off sc0 sc1\n\t"
    "s_waitcnt vmcnt(3)\n\t"
    "v_cmp_eq_u32 vcc, %[tg], v85\n\t"
    "s_xor_b64 %[scr], vcc, exec\n\t"
    "s_cbranch_scc0 F2_%=\n\t"
    "global_load_dwordx2 v[84:85], %[p], off sc1\n\t"
    "s_waitcnt vmcnt(3)\n\t"
    "v_cmp_eq_u32 vcc, %[tg], v87\n\t"
    "s_xor_b64 %[scr], vcc, exec\n\t"
    "s_cbranch_scc0 F3_%=\n\t"
    "global_load_dwordx2 v[86:87], %[p], off sc0 sc1\n\t"

    "s_waitcnt vmcnt(3)\n\t"
    "v_cmp_eq_u32 vcc, %[tg], v81\n\t"
    "s_xor_b64 %[scr], vcc, exec\n\t"
    "s_cbranch_scc0 F0_%=\n\t"
    "global_load_dwordx2 v[80:81], %[p], off sc1\n\t"
    "s_waitcnt vmcnt(3)\n\t"
    "v_cmp_eq_u32 vcc, %[tg], v83\n\t"
    "s_xor_b64 %[scr], vcc, exec\n\t"
    "s_cbranch_scc0 F1_%=\n\t"
    "global_load_dwordx2 v[82:83], %[p], off sc0 sc1\n\t"
    "s_waitcnt vmcnt(3)\n\t"
    "v_cmp_eq_u32 vcc, %[tg], v85\n\t"
    "s_xor_b64 %[scr], vcc, exec\n\t"
    "s_cbranch_scc0 F2_%=\n\t"
    "global_load_dwordx2 v[84:85], %[p], off sc1\n\t"
    "s_waitcnt vmcnt(3)\n\t"
    "v_cmp_eq_u32 vcc, %[tg], v87\n\t"
    "s_xor_b64 %[scr], vcc, exec\n\t"
    "s_cbranch_scc0 F3_%=\n\t"
    "global_load_dwordx2 v[86:87], %[p], off sc0 sc1\n\t"

    "s_waitcnt vmcnt(3)\n\t"
    "v_cmp_eq_u32 vcc, %[tg], v81\n\t"
    "s_xor_b64 %[scr], vcc, exec\n\t"
    "s_cbranch_scc0 F0_%=\n\t"
    "s_waitcnt vmcnt(2)\n\t"
    "v_cmp_eq_u32 vcc, %[tg], v83\n\t"
    "s_xor_b64 %[scr], vcc, exec\n\t"
    "s_cbranch_scc0 F1_%=\n\t"
    "s_waitcnt vmcnt(1)\n\t"
    "v_cmp_eq_u32 vcc, %[tg], v85\n\t"
    "s_xor_b64 %[scr], vcc, exec\n\t"
    "s_cbranch_scc0 F2_%=\n\t"
    "s_waitcnt vmcnt(0)\n\t"
    "v_cmp_eq_u32 vcc, %[tg], v87\n\t"
    "s_xor_b64 %[scr], vcc, exec\n\t"
    "s_cbranch_scc0 F3_%=\n\t"
    "v_mov_b32 %[out], 0\n\t"
    "s_branch DN_%=\n\t"

    "F0_%=:\n\t"
    "v_mov_b32 %[out], v80\n\t"
    "s_mov_b32 %[fnd], 1\n\t"
    "s_branch DN_%=\n\t"
    "F1_%=:\n\t"
    "v_mov_b32 %[out], v82\n\t"
    "s_mov_b32 %[fnd], 1\n\t"
    "s_branch DN_%=\n\t"
    "F2_%=:\n\t"
    "v_mov_b32 %[out], v84\n\t"
    "s_mov_b32 %[fnd], 1\n\t"
    "s_branch DN_%=\n\t"
    "F3_%=:\n\t"
    "v_mov_b32 %[out], v86\n\t"
    "s_mov_b32 %[fnd], 1\n\t"
    "DN_%=:\n\t"
    "s_waitcnt vmcnt(0)"
    : [out]"=&v"(out), [fnd]"=&s"(fnd), [scr]"=&s"(scr)
    : [p]"v"(p), [tg]"v"(tag)
    : "vcc", "scc", "memory",
      "v80","v81","v82","v83","v84","v85","v86","v87");
  *val = out;
  return fnd;
}

#define MFMA_I8(a, b, c) __builtin_amdgcn_mfma_i32_16x16x64_i8(a, b, c, 0, 0, 0)

// ---------------- absmax over a float tensor (n4 = n/4) ----------------
__global__ void k_absmax(const float* __restrict__ p, int n4, unsigned* slot) {
  int i = blockIdx.x * blockDim.x + threadIdx.x;
  int stride = gridDim.x * blockDim.x;
  const v4f* p4 = (const v4f*)p;
  float m = 0.0f;
  for (; i < n4; i += stride) {
    v4f v = p4[i];
    m = fmaxf(m, fmaxf(fmaxf(fabsf(v[0]), fabsf(v[1])),
                       fmaxf(fabsf(v[2]), fabsf(v[3]))));
  }
  m = wave_amax(m);
  if ((threadIdx.x & 63) == 0) atomicMax(slot, __float_as_uint(m));
}

// ---------------- 768x256 weight -> int8 MFMA B-fragments ----------------
__global__ void k_frag(const float* __restrict__ src,
                       const unsigned* __restrict__ slots, int slot_idx,
                       signed char* __restrict__ dst) {
  int id = blockIdx.x * 256 + threadIdx.x;   // 0..49151
  float s = fmaxf(__uint_as_float(slots[slot_idx]) / 127.0f, 1e-8f);
  int bq   = id & 3;
  int lane = (id >> 2) & 63;
  int kc   = (id >> 8) & 3;
  int ct   = id >> 10;
  int n = ct * 16 + (lane & 15);
  int k = kc * 64 + (lane >> 4) * 16 + bq * 4;
  const float* p = src + permj(n) * 256 + k;
  int b0 = ((int)clamp128(rintf(p[0] / s))) & 255;
  int b1 = ((int)clamp128(rintf(p[1] / s))) & 255;
  int b2 = ((int)clamp128(rintf(p[2] / s))) & 255;
  int b3 = ((int)clamp128(rintf(p[3] / s))) & 255;
  ((int*)dst)[id] = b0 | (b1 << 8) | (b2 << 16) | (b3 << 24);
}

// ---------------- biases: reorder + fake-quant (dequantized fp32) ----------
__global__ void k_bias(const float* __restrict__ bih, const float* __restrict__ bhh,
                       const unsigned* __restrict__ slots, float* __restrict__ bqo) {
  int j = threadIdx.x;               // 0..767
  float s_bx = fmaxf(__uint_as_float(slots[3]) / 127.0f, 1e-8f);
  float s_br = fmaxf(__uint_as_float(slots[4]) / 127.0f, 1e-8f);
  int pr = permj(j);
  bqo[j]       = s_bx * clamp128(rintf(bih[pr] / s_bx));
  bqo[768 + j] = s_br * clamp128(rintf(bhh[pr] / s_br));
}

// ---------------- quantize x -> int8 ----------------
__global__ void k_xq(const float* __restrict__ x, const unsigned* __restrict__ slots,
                     signed char* __restrict__ xq8, int n4) {
  int i = blockIdx.x * blockDim.x + threadIdx.x;
  if (i >= n4) return;
  float s_x = fmaxf(__uint_as_float(slots[0]) / 127.0f, 1e-8f);
  v4f v = ((const v4f*)x)[i];
  int b0 = ((int)clamp128(rintf(v[0] / s_x))) & 255;
  int b1 = ((int)clamp128(rintf(v[1] / s_x))) & 255;
  int b2 = ((int)clamp128(rintf(v[2] / s_x))) & 255;
  int b3 = ((int)clamp128(rintf(v[3] / s_x))) & 255;
  ((int*)xq8)[i] = b0 | (b1 << 8) | (b2 << 16) | (b3 << 24);
}

// ---------------- Wx GEMM, int8 MFMA (both passes) ----------------
__global__ __launch_bounds__(1024) void k_wx_i8(
    const signed char* __restrict__ xq8, const signed char* __restrict__ wf,
    unsigned* __restrict__ slots, signed char* __restrict__ wxq, int mode) {
  const int t = blockIdx.x;
  const int tid = threadIdx.x, lane = tid & 63, w = tid >> 6;
  const int cl = lane & 15, lh = lane >> 4;

  v4i Bz[4], Br[4], Bn[4];
  #pragma unroll
  for (int kc = 0; kc < 4; ++kc) {
    Bz[kc] = *(const v4i*)(wf + (((w)*4      + kc) * 64 + lane) * 16);
    Br[kc] = *(const v4i*)(wf + (((w + 16)*4 + kc) * 64 + lane) * 16);
    Bn[kc] = *(const v4i*)(wf + (((w + 32)*4 + kc) * 64 + lane) * 16);
  }
  v4i acc[3][4];
  #pragma unroll
  for (int p = 0; p < 3; ++p)
    #pragma unroll
    for (int rt = 0; rt < 4; ++rt) acc[p][rt] = (v4i){0, 0, 0, 0};

  const signed char* xr = xq8 + t * 16384;
  #pragma unroll
  for (int kc = 0; kc < 4; ++kc)
    #pragma unroll
    for (int rt = 0; rt < 4; ++rt) {
      v4i A = *(const v4i*)(xr + (rt * 16 + cl) * 256 + kc * 64 + lh * 16);
      acc[0][rt] = MFMA_I8(A, Bz[kc], acc[0][rt]);
      acc[1][rt] = MFMA_I8(A, Br[kc], acc[1][rt]);
      acc[2][rt] = MFMA_I8(A, Bn[kc], acc[2][rt]);
    }

  if (mode == 0) {
    int mm = 0;
    #pragma unroll
    for (int p = 0; p < 3; ++p)
      #pragma unroll
      for (int rt = 0; rt < 4; ++rt)
        #pragma unroll
        for (int rg = 0; rg < 4; ++rg) mm = max(mm, abs(acc[p][rt][rg]));
    #pragma unroll
    for (int m = 1; m <= 32; m <<= 1) mm = max(mm, __shfl_xor(mm, m, 64));
    if (lane == 0) atomicMax((int*)(slots + 5), mm);
  } else {
    int islot = *(const int*)(slots + 5);
    float maxMf = (float)islot;
    float s_x = fmaxf(__uint_as_float(slots[0]) / 127.0f, 1e-8f);
    float s_W = fmaxf(__uint_as_float(slots[1]) / 127.0f, 1e-8f);
    float s_xW = s_x * s_W;
    float s_wx = fmaxf(s_xW * maxMf / 127.0f, 1e-8f);
    #pragma unroll
    for (int p = 0; p < 3; ++p)
      #pragma unroll
      for (int rt = 0; rt < 4; ++rt) {
        int dw = 0;
        #pragma unroll
        for (int rg = 0; rg < 4; ++rg) {
          float qf = clamp128(rintf((s_xW * (float)acc[p][rt][rg]) / s_wx));
          dw |= (((int)qf) & 255) << (rg * 8);
        }
        ((int*)wxq)[t * 12288 + p * 4096 + rt * 1024 + w * 64 + lh * 16 + cl] = dw;
      }
  }
}

// ---------------- cross-WG max exchange (DPP reduce + burst polling) -------
// Slot = aligned 8B {tag:hi32, value:lo32}; one per (parity, wg, channel);
// per-WG slot block = 64B.  All waves DPP-reduce each channel (VALU-only);
// lane 63 LDS-atomicMaxes the wave max.  Writers: tid<NCH publish once
// (relaxed AGENT store).  Pollers: one lane per remote-wg x channel
// alternates {bounded pipelined asm burst} and {proven __hip_atomic_load
// AGENT probe} until tag match, then LDS-atomicMax the value.  2 lgkm-only
// barriers/round; 3-ring LDS sets; parity-2 slots; monotone tags => no ABA.
template <int NCH>
__device__ __forceinline__ void xchg(unsigned* keys, unsigned tag,
    unsigned (*lred)[8], unsigned long long* gslot, int wg, int tid, int lane) {
  const int rset = tag % 3;
  #pragma unroll
  for (int c = 0; c < NCH; ++c) keys[c] = dpp_wave_max(keys[c]);
  if (lane == 63) {
    #pragma unroll
    for (int c = 0; c < NCH; ++c) atomicMax(&lred[rset][c], keys[c]);
  }
  bar_lgkm();
  const int par = tag & 1;
  if (tid < NCH) {
    unsigned long long v =
        ((unsigned long long)tag << 32) | (unsigned long long)lred[rset][tid];
    __hip_atomic_store(&gslot[(par * NWG + wg) * 8 + tid], v,
                       __ATOMIC_RELAXED, __HIP_MEMORY_SCOPE_AGENT);
  } else if (tid == 32) {
    int ns = rset + 1; if (ns == 3) ns = 0;       // pre-zero next ring set
    #pragma unroll
    for (int c = 0; c < 8; ++c) lred[ns][c] = 0u;
  } else if (tid >= 64 && tid < 64 + (NWG - 1) * NCH) {
    int idx = tid - 64;
    int owi = idx / NCH;
    int c = idx - owi * NCH;
    int ow = owi + (owi >= wg ? 1 : 0);
    unsigned long long* p = &gslot[(par * NWG + ow) * 8 + c];
    unsigned val;
    for (;;) {
      if (poll_burst(p, tag, &val)) break;           // fast staggered samples
      unsigned long long v =                         // proven liveness probe
          __hip_atomic_load(p, __ATOMIC_RELAXED, __HIP_MEMORY_SCOPE_AGENT);
      if ((unsigned)(v >> 32) == tag) { val = (unsigned)v; break; }
    }
    atomicMax(&lred[rset][c], val);
  }
  bar_lgkm();
  #pragma unroll
  for (int c = 0; c < NCH; ++c) keys[c] = lred[rset][c];
}

// ---------------- the recurrence: 8 workgroups, 8 batch rows each ----------
__global__ __launch_bounds__(512, 1) void k_recur8(
    const signed char* __restrict__ wxq, const signed char* __restrict__ brf,
    const float* __restrict__ bq, const unsigned* __restrict__ slots,
    const float* __restrict__ h0p, float* __restrict__ out,
    unsigned long long* __restrict__ gslot) {
  __shared__ signed char ah[16 * 272];     // rows 0..7 real, 8..15 zero
  __shared__ int zs[8 * 256];              // scattered acc, gate z [row][col]
  __shared__ int rs_[8 * 256];             // gate r
  __shared__ int ns_[8 * 256];             // gate n
  __shared__ unsigned lred[3][8];          // 3-set ring x 8 channels

  const int tid = threadIdx.x;
  const int lane = tid & 63;
  const int w = tid >> 6;                  // 8 waves; wave w: col tiles {2w,2w+1}
  const int cl = lane & 15;
  const int lh = lane >> 4;
  const int wg = blockIdx.x;               // 0..7 -> batch rows 8*wg..+7
  const int j = tid & 255;                 // elementwise column 0..255
  const int rblk = tid >> 8;               // 0/1: local rows 4*rblk..+3

  // zero lred + whole ah (rows 8..15 stay zero forever)
  if (tid < 24) ((unsigned*)lred)[tid] = 0u;
  for (int i = tid; i < 1088; i += 512) ((int*)ah)[i] = 0;

  float s_x = fmaxf(__uint_as_float(slots[0]) / 127.0f, 1e-8f);
  float s_W = fmaxf(__uint_as_float(slots[1]) / 127.0f, 1e-8f);
  float s_R = fmaxf(__uint_as_float(slots[2]) / 127.0f, 1e-8f);
  float maxM0 = (float)(*(const int*)(slots + 5));
  float s_wx = fmaxf(s_x * s_W * maxM0 / 127.0f, 1e-8f);

  float bxz = bq[j], bxr = bq[j + 256], bxn = bq[j + 512];
  float brz = bq[768 + j], brr = bq[1024 + j], brn = bq[1280 + j];

  // R fragments, resident: 2 col-tiles x 3 gates x 4 kc
  v4i Bz[2][4], Br[2][4], Bn[2][4];
  #pragma unroll
  for (int cg = 0; cg < 2; ++cg) {
    int ct = w * 2 + cg;
    #pragma unroll
    for (int kc = 0; kc < 4; ++kc) {
      Bz[cg][kc] = *(const v4i*)(brf + ((ct * 4        + kc) * 64 + lane) * 16);
      Br[cg][kc] = *(const v4i*)(brf + (((ct + 16) * 4 + kc) * 64 + lane) * 16);
      Bn[cg][kc] = *(const v4i*)(brf + (((ct + 32) * 4 + kc) * 64 + lane) * 16);
    }
  }

  float h[4];
  #pragma unroll
  for (int rg = 0; rg < 4; ++rg)
    h[rg] = h0p[(wg * 8 + rblk * 4 + rg) * 256 + j];

  __syncthreads();                         // init (once; full sync fine)

  unsigned tag = 1;
  float sh;
  {
    float m = fmaxf(fmaxf(fabsf(h[0]), fabsf(h[1])),
                    fmaxf(fabsf(h[2]), fabsf(h[3])));
    unsigned kk[1] = {__float_as_uint(m)};
    xchg<1>(kk, tag++, lred, gslot, wg, tid, lane);
    sh = fmaxf(__uint_as_float(kk[0]) / 127.0f, 1e-8f);
    float ish = 1.0f / sh;
    #pragma unroll
    for (int rg = 0; rg < 4; ++rg)
      ah[(rblk * 4 + rg) * 272 + j] = (signed char)(int)rintf(h[rg] * ish);
    bar_lgkm();
  }

  // wxq dword index: global rows 8wg+4rblk..+3 = rt*16 + lhb*4..+3
  const int rt_ = wg >> 1;
  const int lhb = ((wg & 1) << 1) | rblk;
  const int widx0 = rt_ * 1024 + (j >> 4) * 64 + lhb * 16 + (j & 15);

  for (int t = 0; t < T_STEPS; ++t) {
    // Wx code dwords for this thread's 4 rows x 3 gates
    const int* wxi = (const int*)wxq + (size_t)t * 12288 + widx0;
    int wvz = wxi[0];
    int wvr = wxi[4096];
    int wvn = wxi[8192];

    // ---- GEMM: rows 0..7 real (rows 8..15 of ah are zero) ----
    v4i aZ[2] = {(v4i){0,0,0,0}, (v4i){0,0,0,0}};
    v4i aR[2] = {(v4i){0,0,0,0}, (v4i){0,0,0,0}};
    v4i aN[2] = {(v4i){0,0,0,0}, (v4i){0,0,0,0}};
    #pragma unroll
    for (int kc = 0; kc < 4; ++kc) {
      v4i A = *(const v4i*)(ah + cl * 272 + kc * 64 + lh * 16);
      #pragma unroll
      for (int cg = 0; cg < 2; ++cg) {
        aZ[cg] = MFMA_I8(A, Bz[cg][kc], aZ[cg]);
        aR[cg] = MFMA_I8(A, Br[cg][kc], aR[cg]);
        aN[cg] = MFMA_I8(A, Bn[cg][kc], aN[cg]);
      }
    }

    // scatter real accs (lanes 0..31 hold rows 0..7) into LDS; the round's
    // barriers order these writes before the stage-B reads.
    if (lane < 32) {
      #pragma unroll
      for (int cg = 0; cg < 2; ++cg) {
        int jj = (w * 2 + cg) * 16 + cl;
        #pragma unroll
        for (int rg = 0; rg < 4; ++rg) {
          int row = lh * 4 + rg;
          zs[row * 256 + jj] = aZ[cg][rg];
          rs_[row * 256 + jj] = aR[cg][rg];
          ns_[row * 256 + jj] = aN[cg][rg];
        }
      }
    }

    // ---- R1: global max|acc| (zero rows contribute exactly 0) ----
    int mm = 0;
    #pragma unroll
    for (int cg = 0; cg < 2; ++cg)
      #pragma unroll
      for (int rg = 0; rg < 4; ++rg)
        mm = max(mm, max(abs(aZ[cg][rg]),
                         max(abs(aR[cg][rg]), abs(aN[cg][rg]))));
    unsigned kk[5];
    kk[0] = (unsigned)mm;
    xchg<1>(kk, tag++, lred, gslot, wg, tid, lane);
    float maxMf = (float)(int)kk[0];
    float s_Rh = fmaxf(sh * s_R * maxMf / 127.0f, 1e-8f);
    float fRh = (sh * s_R) / s_Rh;

    // ---- stage B: z_pre, r_pre, Rh_n+br_n + abs/signed maxes ----
    float zp[4], rp[4], nb[4];
    float az = 0.0f, ar = 0.0f, an = 0.0f;
    float mzs = -3.402823466e38f, mrs = -3.402823466e38f;
    #pragma unroll
    for (int rg = 0; rg < 4; ++rg) {
      int row = rblk * 4 + rg;
      float Rz = s_Rh * rintf((float)zs[row * 256 + j] * fRh);
      float Rr = s_Rh * rintf((float)rs_[row * 256 + j] * fRh);
      float Rn = s_Rh * rintf((float)ns_[row * 256 + j] * fRh);
      float wz = s_wx * (float)((signed char)(wvz >> (rg * 8)));
      float wr = s_wx * (float)((signed char)(wvr >> (rg * 8)));
      float a1 = ((wz + bxz) + Rz) + brz;
      float a2 = ((wr + bxr) + Rr) + brr;
      float a3 = Rn + brn;
      zp[rg] = a1; rp[rg] = a2; nb[rg] = a3;
      az = fmaxf(az, fabsf(a1)); ar = fmaxf(ar, fabsf(a2));
      an = fmaxf(an, fabsf(a3));
      mzs = fmaxf(mzs, a1); mrs = fmaxf(mrs, a2);
    }
    kk[0] = __float_as_uint(az); kk[1] = __float_as_uint(ar);
    kk[2] = __float_as_uint(an); kk[3] = skey(mzs); kk[4] = skey(mrs);
    xchg<5>(kk, tag++, lred, gslot, wg, tid, lane);
    float s1 = fmaxf(__uint_as_float(kk[0]) / 127.0f, 1e-8f), i1 = 1.0f / s1;
    float s2 = fmaxf(__uint_as_float(kk[1]) / 127.0f, 1e-8f), i2 = 1.0f / s2;
    float s3 = fmaxf(__uint_as_float(kk[2]) / 127.0f, 1e-8f), i3 = 1.0f / s3;
    float zq_max = s1 * rintf(sdec(kk[3]) * i1);
    float rq_max = s2 * rintf(sdec(kk[4]) * i2);
    float s4 = fmaxf(sigmoidf_(zq_max) / 127.0f, 1e-8f), i4 = 1.0f / s4;
    float s5 = fmaxf(sigmoidf_(rq_max) / 127.0f, 1e-8f), i5 = 1.0f / s5;

    // ---- stage C: z final, rRh ----
    float zf[4], rr_[4];
    float m6 = 0.0f;
    #pragma unroll
    for (int rg = 0; rg < 4; ++rg) {
      float zq = s1 * rintf(zp[rg] * i1);
      float rq = s2 * rintf(rp[rg] * i2);
      float zv = sigmoidf_(zq);
      float rv = sigmoidf_(rq);
      zf[rg] = s4 * rintf(zv * i4);
      float rq2 = s5 * rintf(rv * i5);
      float nbq = s3 * rintf(nb[rg] * i3);
      float rr = rq2 * nbq;
      rr_[rg] = rr;
      m6 = fmaxf(m6, fabsf(rr));
    }
    kk[0] = __float_as_uint(m6);
    xchg<1>(kk, tag++, lred, gslot, wg, tid, lane);
    float s6 = fmaxf(__uint_as_float(kk[0]) / 127.0f, 1e-8f), i6 = 1.0f / s6;

    // ---- stage D: g_pre ----
    float gp[4];
    float m7 = 0.0f;
    #pragma unroll
    for (int rg = 0; rg < 4; ++rg) {
      float rrq = s6 * rintf(rr_[rg] * i6);
      float wn = s_wx * (float)((signed char)(wvn >> (rg * 8)));
      float g = (wn + bxn) + rrq;
      gp[rg] = g;
      m7 = fmaxf(m7, fabsf(g));
    }
    kk[0] = __float_as_uint(m7);
    xchg<1>(kk, tag++, lred, gslot, wg, tid, lane);
    float m7g = __uint_as_float(kk[0]);
    float s7 = fmaxf(m7g / 127.0f, 1e-8f), i7 = 1.0f / s7;
    float gq_max = s7 * rintf(m7g * i7);
    float s8 = fmaxf(tanhf_(gq_max) / 127.0f, 1e-8f), i8v = 1.0f / s8;

    // ---- stage E: g, old/new contribs ----
    float ov[4], nv[4];
    float mo = 0.0f, mn = 0.0f;
    #pragma unroll
    for (int rg = 0; rg < 4; ++rg) {
      float gpq = s7 * rintf(gp[rg] * i7);
      float gv = tanhf_(gpq);
      float gq = s8 * rintf(gv * i8v);
      float o = zf[rg] * h[rg];
      float n = (1.0f - zf[rg]) * gq;
      ov[rg] = o; nv[rg] = n;
      mo = fmaxf(mo, fabsf(o)); mn = fmaxf(mn, fabsf(n));
    }
    kk[0] = __float_as_uint(mo); kk[1] = __float_as_uint(mn);
    xchg<2>(kk, tag++, lred, gslot, wg, tid, lane);
    float s9  = fmaxf(__uint_as_float(kk[0]) / 127.0f, 1e-8f), i9  = 1.0f / s9;
    float s10 = fmaxf(__uint_as_float(kk[1]) / 127.0f, 1e-8f), i10 = 1.0f / s10;

    // ---- stage F: h_new, write output ----
    float mh = 0.0f;
    #pragma unroll
    for (int rg = 0; rg < 4; ++rg) {
      float oq = s9  * rintf(ov[rg] * i9);
      float nq = s10 * rintf(nv[rg] * i10);
      float hn = oq + nq;
      h[rg] = hn;
      mh = fmaxf(mh, fabsf(hn));
      out[t * 16384 + (wg * 8 + rblk * 4 + rg) * 256 + j] = hn;
    }
    kk[0] = __float_as_uint(mh);
    xchg<1>(kk, tag++, lred, gslot, wg, tid, lane);
    sh = fmaxf(__uint_as_float(kk[0]) / 127.0f, 1e-8f);
    float ish = 1.0f / sh;
    #pragma unroll
    for (int rg = 0; rg < 4; ++rg)
      ah[(rblk * 4 + rg) * 272 + j] = (signed char)(int)rintf(h[rg] * ish);
    bar_lgkm();                            // ah ready for next step
  }

  // h_last
  #pragma unroll
  for (int rg = 0; rg < 4; ++rg)
    out[OUT_MAIN_FLOATS + (wg * 8 + rblk * 4 + rg) * 256 + j] = h[rg];
}

// ============================================================================
extern "C" void kernel_launch(void* const* d_in, const int* in_sizes, int n_in,
                              void* d_out, int out_size, void* d_ws, size_t ws_size,
                              hipStream_t stream) {
  const float* x   = (const float*)d_in[0];   // (1024,64,256)
  const float* wih = (const float*)d_in[1];   // (768,256)
  const float* whh = (const float*)d_in[2];   // (768,256)
  const float* bih = (const float*)d_in[3];   // (768,)
  const float* bhh = (const float*)d_in[4];   // (768,)
  const float* h0  = (const float*)d_in[5];   // (64,256)
  float* out = (float*)d_out;

  // d_ws layout: [0..255] absmax slots; [512..1535] tagged exchange slots
  // (2 parity x 8 wg x 8 ch x 8B = 1024B, 64B line per WG); [4096..] bq;
  // [10240..] fragment buffer F (196,608B).
  unsigned* slots = (unsigned*)d_ws;
  unsigned long long* gslot = (unsigned long long*)((char*)d_ws + 512);
  float* bq       = (float*)((char*)d_ws + 4096);
  signed char* F  = (signed char*)d_ws + 10240;

  signed char* wxq = (signed char*)d_out + WXQ_DOUT_OFF; // tail of d_out
  signed char* xq8 = (signed char*)d_out;                // head (dead later)

  hipMemsetAsync(d_ws, 0, 4096, stream);

  k_absmax<<<dim3(1024), dim3(256), 0, stream>>>(x,   16777216 / 4, slots + 0);
  k_absmax<<<dim3(96),   dim3(256), 0, stream>>>(wih, 196608 / 4,   slots + 1);
  k_absmax<<<dim3(96),   dim3(256), 0, stream>>>(whh, 196608 / 4,   slots + 2);
  k_absmax<<<dim3(1),    dim3(256), 0, stream>>>(bih, 768 / 4,      slots + 3);
  k_absmax<<<dim3(1),    dim3(256), 0, stream>>>(bhh, 768 / 4,      slots + 4);

  k_frag<<<dim3(192), dim3(256), 0, stream>>>(wih, slots, 1, F);   // W frags
  k_bias<<<dim3(1), dim3(768), 0, stream>>>(bih, bhh, slots, bq);
  k_xq<<<dim3(16384), dim3(256), 0, stream>>>(x, slots, xq8, 4194304);

  k_wx_i8<<<dim3(1024), dim3(1024), 0, stream>>>(xq8, F, slots, wxq, 0);
  k_wx_i8<<<dim3(1024), dim3(1024), 0, stream>>>(xq8, F, slots, wxq, 1);

  k_frag<<<dim3(192), dim3(256), 0, stream>>>(whh, slots, 2, F);   // R frags

  k_recur8<<<dim3(NWG), dim3(512), 0, stream>>>(wxq, F, bq, slots, h0, out,
                                                gslot);
}